// Round 5
// baseline (428.838 us; speedup 1.0000x reference)
//
#include <hip/hip_runtime.h>
#include <hip/hip_bf16.h>
#include <stdint.h>

typedef __bf16 bf16_t;
typedef __bf16 bf16x8 __attribute__((ext_vector_type(8)));
typedef __bf16 bf16x4 __attribute__((ext_vector_type(4)));
typedef float f32x4 __attribute__((ext_vector_type(4)));
typedef float f32x16 __attribute__((ext_vector_type(16)));

#define NPIX 4096
#define CH 256

// ---------------- GroupNorm stats (2-stage) ----------------
__global__ __launch_bounds__(256) void gn_partial_k(const float* __restrict__ x,
                                                    float* __restrict__ acc2) {
  int bg = blockIdx.x >> 3;
  int chunk = blockIdx.x & 7;
  const float4* xp = (const float4*)(x + (size_t)bg * 32 * NPIX) + chunk * (32 * NPIX / 4 / 8);
  float s = 0.f, ss = 0.f;
  for (int i = threadIdx.x; i < 32 * NPIX / 4 / 8; i += 256) {
    float4 v = xp[i];
    s  += v.x + v.y + v.z + v.w;
    ss += v.x * v.x + v.y * v.y + v.z * v.z + v.w * v.w;
  }
  int l = threadIdx.x & 63, w = threadIdx.x >> 6;
  #pragma unroll
  for (int off = 32; off; off >>= 1) { s += __shfl_down(s, off); ss += __shfl_down(ss, off); }
  __shared__ float rs[4], rss[4];
  if (l == 0) { rs[w] = s; rss[w] = ss; }
  __syncthreads();
  if (threadIdx.x == 0) {
    atomicAdd(&acc2[bg * 2],     rs[0] + rs[1] + rs[2] + rs[3]);
    atomicAdd(&acc2[bg * 2 + 1], rss[0] + rss[1] + rss[2] + rss[3]);
  }
}

__global__ void gn_finalize_k(const float* __restrict__ acc2, float* __restrict__ stats) {
  int bg = threadIdx.x;  // 64 threads
  float mean = acc2[bg * 2] * (1.f / (32.f * NPIX));
  float var  = acc2[bg * 2 + 1] * (1.f / (32.f * NPIX)) - mean * mean;
  stats[bg * 2]     = mean;
  stats[bg * 2 + 1] = rsqrtf(var + 1e-5f);
}

// ------------- normalize + transpose [b][c][p] -> bf16 [b][p][c] -------------
__global__ __launch_bounds__(256) void gn_apply_t_k(const float* __restrict__ x,
    const float* __restrict__ stats, const float* __restrict__ gamma,
    const float* __restrict__ beta, bf16_t* __restrict__ xnT) {
  __shared__ float tile[32][33];
  int b = blockIdx.z;
  int p0 = blockIdx.x * 32, c0 = blockIdx.y * 32;
  int g = c0 >> 5;
  float mean = stats[(b * 8 + g) * 2], rstd = stats[(b * 8 + g) * 2 + 1];
  int tx = threadIdx.x, ty = threadIdx.y;
  const float* xb = x + ((size_t)b * CH + c0) * NPIX + p0;
  #pragma unroll
  for (int j = 0; j < 4; ++j) {
    int c = ty + j * 8;
    float v = xb[(size_t)c * NPIX + tx];
    tile[c][tx] = (v - mean) * rstd * gamma[c0 + c] + beta[c0 + c];
  }
  __syncthreads();
  bf16_t* op = xnT + ((size_t)b * NPIX + p0) * CH + c0;
  #pragma unroll
  for (int j = 0; j < 4; ++j) {
    int p = ty + j * 8;
    op[(size_t)p * CH + tx] = (bf16_t)tile[tx][p];
  }
}

// ---------------- cast weights to bf16 ----------------
__global__ __launch_bounds__(256) void cast_w_k(const float* __restrict__ wq,
    const float* __restrict__ wp, bf16_t* __restrict__ wqb, bf16_t* __restrict__ wpb) {
  int i = blockIdx.x * 256 + threadIdx.x;
  if (i < 768 * 256) wqb[i] = (bf16_t)wq[i];
  if (i < 256 * 256) wpb[i] = (bf16_t)wp[i];
}

// ---------------- NT GEMM (modes 0,3) ----------------
#define LSTR 80

template <int MODE>
__global__ __launch_bounds__(256) void gemm_nt_k(
    const bf16_t* __restrict__ Ag, const bf16_t* __restrict__ Bg,
    int lda, int ldb, int K,
    void* __restrict__ O0, void* __restrict__ O1,
    const float* __restrict__ bias, const float* __restrict__ resid) {
  __shared__ __align__(16) char ldsA[128 * LSTR];
  __shared__ __align__(16) char ldsB[128 * LSTR];

  const int t = threadIdx.x;
  const int l = t & 63;
  const int w = t >> 6;
  const int wr = w >> 1, wc = w & 1;
  const int bm = blockIdx.x * 128;
  const int bn = blockIdx.y * 128;
  const int bz = blockIdx.z;

  const bf16_t* Ap = Ag;
  const bf16_t* Bp = Bg;
  if constexpr (MODE == 0) Ap += (size_t)bz * NPIX * CH;
  if constexpr (MODE == 3) Bp += (size_t)bz * NPIX * CH;

  f32x4 acc[4][4] = {};

  const int srow = t >> 2;
  const int scol = (t & 3) * 8;

  for (int k0 = 0; k0 < K; k0 += 32) {
    __syncthreads();
    #pragma unroll
    for (int it = 0; it < 2; ++it) {
      int r = it * 64 + srow;
      *(bf16x8*)(ldsA + r * LSTR + scol * 2) =
          *(const bf16x8*)(Ap + (size_t)(bm + r) * lda + k0 + scol);
      *(bf16x8*)(ldsB + r * LSTR + scol * 2) =
          *(const bf16x8*)(Bp + (size_t)(bn + r) * ldb + k0 + scol);
    }
    __syncthreads();
    bf16x8 fa[4], fb[4];
    #pragma unroll
    for (int m = 0; m < 4; ++m)
      fa[m] = *(const bf16x8*)(ldsA + (wr * 64 + m * 16 + (l & 15)) * LSTR + (l >> 4) * 16);
    #pragma unroll
    for (int n = 0; n < 4; ++n)
      fb[n] = *(const bf16x8*)(ldsB + (wc * 64 + n * 16 + (l & 15)) * LSTR + (l >> 4) * 16);
    #pragma unroll
    for (int m = 0; m < 4; ++m)
      #pragma unroll
      for (int n = 0; n < 4; ++n)
        acc[m][n] = __builtin_amdgcn_mfma_f32_16x16x32_bf16(fa[m], fb[n], acc[m][n], 0, 0, 0);
  }

  const int r0 = bm + wr * 64 + (l >> 4) * 4;
  const int c0 = bn + wc * 64 + (l & 15);
  #pragma unroll
  for (int m = 0; m < 4; ++m) {
    #pragma unroll
    for (int n = 0; n < 4; ++n) {
      int col = c0 + n * 16;
      #pragma unroll
      for (int j = 0; j < 4; ++j) {
        int row = r0 + m * 16 + j;
        float v = acc[m][n][j];
        if constexpr (MODE == 0) {
          float val = v + bias[col];
          if (col < 256) val *= 0.09016844006f;  // fold c1=log2e/16 into q
          if (col < 512)
            ((bf16_t*)O0)[(size_t)bz * NPIX * 512 + (size_t)row * 512 + col] = (bf16_t)val;
          else
            ((bf16_t*)O1)[(size_t)bz * CH * NPIX + (size_t)(col - 512) * NPIX + row] = (bf16_t)val;
        } else {
          size_t idx = (size_t)bz * CH * NPIX + (size_t)row * NPIX + col;
          ((float*)O0)[idx] = v + bias[row] + resid[idx];
        }
      }
    }
  }
}

// ---------------- fused flash attention (T15 cross-tile pipeline) ----------------
// 512 threads = 8 waves; wave (g,half): q-group g (32 rows), kv-half of KVB=64.
// Tile t: stageV(t+1) -> QK(t) -> bar1 -> stageK(t+1) -> [PV(t-1) || softmax(t)]
//         -> rescale -> bar2.  K single-buffer 32KB, V 3-slot 96KB.
#define KVB 64
#define KBYTES 32768   // 64 kv rows * 512 B
#define VBYTES 32768   // 256 c rows * 128 B

__device__ __forceinline__ void dma16(const void* g, void* l) {
  __builtin_amdgcn_global_load_lds(
      (const __attribute__((address_space(1))) unsigned int*)g,
      (__attribute__((address_space(3))) unsigned int*)l, 16, 0, 0);
}

__device__ inline unsigned int pack2bf(float lo, float hi) {
  unsigned short a = __builtin_bit_cast(unsigned short, (bf16_t)lo);
  unsigned short b = __builtin_bit_cast(unsigned short, (bf16_t)hi);
  return (unsigned int)a | ((unsigned int)b << 16);
}

__global__ __launch_bounds__(512, 2) void flash_k(
    const bf16_t* __restrict__ qkT, const bf16_t* __restrict__ vglob,
    bf16_t* __restrict__ OT) {
  __shared__ __align__(16) char kS[KBYTES];
  __shared__ __align__(16) char vS[3 * VBYTES];
  __shared__ float mls[8][2][32];

  const int t = threadIdx.x;
  const int l = t & 63, w = t >> 6;       // w 0..7
  const int lq = l & 31, h = l >> 5;
  const int g = w >> 1, half = w & 1;
  const int batch = blockIdx.x & 7;        // one batch per XCD
  const int q0 = (blockIdx.x >> 3) * 128;

  const bf16_t* qk_b = qkT + (size_t)batch * NPIX * 512;
  const bf16_t* v_b  = vglob + (size_t)batch * CH * NPIX;

  // Q fragments (persistent, pre-scaled by c1): Q[q0+g*32+lq][kk*16 + h*8 +: 8]
  bf16x8 qf[16];
  const bf16_t* qrow = qk_b + (size_t)(q0 + g * 32 + lq) * 512 + h * 8;
  #pragma unroll
  for (int kk = 0; kk < 16; ++kk) qf[kk] = *(const bf16x8*)(qrow + kk * 16);

  // DMA lane geometry (wave-uniform LDS base + lane*16 linear dest)
  const int krow_l = w * 8 + (l >> 5);   // + it*2
  const int kslot  = l & 31;
  const int vrow_l = w * 32 + (l >> 3);  // + it*8
  const int vslot  = l & 7;
  const bf16_t* ksrc = qk_b + 256;

  auto stage_k = [&](int tile) {
    #pragma unroll
    for (int it = 0; it < 4; ++it) {
      int r = krow_l + it * 2;
      dma16(ksrc + (size_t)(tile * KVB + r) * 512 + ((kslot ^ (r & 31)) << 3),
            kS + (w * 8 + it * 2) * 512);
    }
  };
  auto stage_v = [&](int tile, int slot) {
    #pragma unroll
    for (int it = 0; it < 4; ++it) {
      int c = vrow_l + it * 8;
      dma16(v_b + (size_t)c * NPIX + tile * KVB + ((vslot ^ (c & 7)) << 3),
            vS + slot * VBYTES + (w * 32 + it * 8) * 128);
    }
  };

  stage_k(0);
  stage_v(0, 0);
  __syncthreads();

  f32x16 acc_o[8] = {};
  float m = -1e30f, lsum = 0.f;
  const int krow = half * 32 + lq;
  const char* kbase = kS + krow * 512;
  const int kxor = (h << 4) ^ (lq << 4);                              // bits 4-8
  const int vxor = (half << 6) ^ (h << 4) ^ ((lq & 7) << 4);          // bits 4-6
  const char* vlane = vS + lq * 128;

  bf16x8 paA[2];   // P(t-1) fragments

  auto pv = [&](int slot) {
    const char* vb = vlane + slot * VBYTES;
    __builtin_amdgcn_s_setprio(1);
    #pragma unroll
    for (int kk2 = 0; kk2 < 2; ++kk2) {
      const char* vp = vb + (vxor ^ (kk2 << 5));
      #pragma unroll
      for (int n2 = 0; n2 < 8; ++n2) {
        bf16x8 vf = *(const bf16x8*)(vp + n2 * 4096);
        acc_o[n2] = __builtin_amdgcn_mfma_f32_32x32x16_bf16(paA[kk2], vf, acc_o[n2], 0, 0, 0);
      }
    }
    __builtin_amdgcn_s_setprio(0);
  };

  for (int tile = 0; tile < 64; ++tile) {
    if (tile < 63) stage_v(tile + 1, (tile + 1) % 3);

    // QK^T (swapped): s = S^T[kv = half*32 + crow(r,h)][q = lq], pre-scaled (c1 in Q)
    f32x16 s = {};
    __builtin_amdgcn_s_setprio(1);
    #pragma unroll
    for (int kk = 0; kk < 16; ++kk) {
      bf16x8 kf = *(const bf16x8*)(kbase + (kxor ^ (kk << 5)));
      s = __builtin_amdgcn_mfma_f32_32x32x16_bf16(kf, qf[kk], s, 0, 0, 0);
    }
    __builtin_amdgcn_s_setprio(0);
    __syncthreads();                 // all QK reads of kS done (+drains stage_v)
    if (tile < 63) stage_k(tile + 1);

    // softmax head: max + defer decision (no acc_o touch yet)
    float tmax = s[0];
    #pragma unroll
    for (int r = 1; r < 16; ++r) tmax = fmaxf(tmax, s[r]);
    tmax = fmaxf(tmax, __shfl_xor(tmax, 32, 64));
    const bool need = !__all(tmax <= m + 10.f);
    float mnew = m, sc = 1.f;
    if (need) { mnew = fmaxf(m, tmax); sc = exp2f(m - mnew); }

    // PV(t-1) in old scale (independent of softmax tail -> scheduler overlaps)
    if (tile > 0) pv((tile + 2) % 3);

    // softmax tail: exp, row-sum, pack P(t) -> paB
    float ls = 0.f;
    #pragma unroll
    for (int r = 0; r < 16; ++r) { float p = exp2f(s[r] - mnew); s[r] = p; ls += p; }
    ls += __shfl_xor(ls, 32, 64);

    bf16x8 paB[2];
    #pragma unroll
    for (int kk2 = 0; kk2 < 2; ++kk2) {
      const int hi = kk2 * 8;
      unsigned int wkeep[2], wsend[2];
      #pragma unroll
      for (int j = 0; j < 2; ++j) {
        float a0 = s[2 * j + hi],     b0 = s[2 * j + 1 + hi];
        float a1 = s[2 * j + 4 + hi], b1 = s[2 * j + 5 + hi];
        float ka = h ? a1 : a0, kb = h ? b1 : b0;
        float sa = h ? a0 : a1, sb = h ? b0 : b1;
        wkeep[j] = pack2bf(ka, kb);
        wsend[j] = pack2bf(sa, sb);
      }
      unsigned int wr0 = __shfl_xor(wsend[0], 32, 64);
      unsigned int wr1 = __shfl_xor(wsend[1], 32, 64);
      union { unsigned int u[4]; bf16x8 v; } pu;
      pu.u[0] = h ? wr0 : wkeep[0];
      pu.u[1] = h ? wr1 : wkeep[1];
      pu.u[2] = h ? wkeep[0] : wr0;
      pu.u[3] = h ? wkeep[1] : wr1;
      paB[kk2] = pu.v;
    }

    // rescale AFTER PV(t-1) landed in acc_o
    if (need) {
      #pragma unroll
      for (int n2 = 0; n2 < 8; ++n2)
        #pragma unroll
        for (int r = 0; r < 16; ++r) acc_o[n2][r] *= sc;
    }
    lsum = lsum * sc + ls;
    m = mnew;
    paA[0] = paB[0]; paA[1] = paB[1];

    __syncthreads();                 // drains K(t+1)/V(t+1); protects kS & V slots
  }
  pv(0);                             // PV(63), V slot 63%3 == 0
  __syncthreads();                   // all PV reads done before scratch reuse

  // ---- merge wave pairs (2g, 2g+1): complementary kv halves ----
  if (h == 0) { mls[w][0][lq] = m; mls[w][1][lq] = lsum; }
  char* abuf = (g == 0) ? kS : (vS + (g - 1) * VBYTES);
  if (half == 1) {
    float* ab = (float*)abuf + l * 128;
    #pragma unroll
    for (int n2 = 0; n2 < 8; ++n2)
      #pragma unroll
      for (int q4 = 0; q4 < 4; ++q4) {
        f32x4 vv;
        vv[0] = acc_o[n2][q4 * 4 + 0]; vv[1] = acc_o[n2][q4 * 4 + 1];
        vv[2] = acc_o[n2][q4 * 4 + 2]; vv[3] = acc_o[n2][q4 * 4 + 3];
        *(f32x4*)(ab + n2 * 16 + q4 * 4) = vv;
      }
  }
  __syncthreads();
  if (half == 0) {
    float mB = mls[w + 1][0][lq], lB = mls[w + 1][1][lq];
    float mS = fmaxf(m, mB);
    float sA = exp2f(m - mS), sB = exp2f(mB - mS);
    float inv = 1.f / (lsum * sA + lB * sB);
    const float* ab = (const float*)abuf + l * 128;
    bf16_t* obase = OT + (size_t)batch * NPIX * CH + (size_t)(q0 + g * 32) * CH + lq;
    #pragma unroll
    for (int r = 0; r < 16; ++r) {
      int q = (r & 3) + 8 * (r >> 2) + 4 * h;
      float sAr = __shfl(sA, q, 64);
      float sBr = __shfl(sB, q, 64);
      float ivr = __shfl(inv, q, 64);
      bf16_t* orow = obase + (size_t)q * CH;
      #pragma unroll
      for (int n2 = 0; n2 < 8; ++n2) {
        float ob = (acc_o[n2][r] * sAr + ab[n2 * 16 + r] * sBr) * ivr;
        orow[n2 * 32] = (bf16_t)ob;
      }
    }
  }
}

extern "C" void kernel_launch(void* const* d_in, const int* in_sizes, int n_in,
                              void* d_out, int out_size, void* d_ws, size_t ws_size,
                              hipStream_t stream) {
  const float* x      = (const float*)d_in[0];
  const float* gamma  = (const float*)d_in[1];
  const float* beta   = (const float*)d_in[2];
  const float* w_qkv  = (const float*)d_in[3];
  const float* b_qkv  = (const float*)d_in[4];
  const float* w_proj = (const float*)d_in[5];
  const float* b_proj = (const float*)d_in[6];

  char* p = (char*)d_ws;
  auto alloc = [&](size_t bytes) {
    char* r = p;
    p += (bytes + 255) & ~(size_t)255;
    return (void*)r;
  };
  bf16_t* qkT  = (bf16_t*)alloc((size_t)8 * NPIX * 512 * 2);  // 32MB  [b][p][q|k]
  bf16_t* vbuf = (bf16_t*)alloc((size_t)8 * CH * NPIX * 2);   // 16MB  [b][c][p]
  bf16_t* OT   = (bf16_t*)alloc((size_t)8 * NPIX * CH * 2);   // 16MB  [b][p][c]
  bf16_t* wqb  = (bf16_t*)alloc(768 * 256 * 2);
  bf16_t* wpb  = (bf16_t*)alloc(256 * 256 * 2);
  float*  acc2 = (float*)alloc(64 * 2 * 4);
  float*  stats= (float*)alloc(64 * 2 * 4);
  bf16_t* xnT  = (bf16_t*)d_out;  // scratch: dead before final proj writes d_out

  hipMemsetAsync(acc2, 0, 64 * 2 * 4, stream);
  gn_partial_k<<<64 * 8, 256, 0, stream>>>(x, acc2);
  gn_finalize_k<<<1, 64, 0, stream>>>(acc2, stats);
  gn_apply_t_k<<<dim3(128, 8, 8), dim3(32, 8), 0, stream>>>(x, stats, gamma, beta, xnT);
  cast_w_k<<<768, 256, 0, stream>>>(w_qkv, w_proj, wqb, wpb);

  // QKV: [p][o] = xnT[p][c] . w_qkv[o][c]  (q pre-scaled by c1 in epilogue)
  gemm_nt_k<0><<<dim3(32, 6, 8), 256, 0, stream>>>(xnT, wqb, CH, CH, CH,
                                                   qkT, vbuf, b_qkv, nullptr);
  // fused attention (all batches): 256 blocks x 512 thr
  flash_k<<<256, 512, 0, stream>>>(qkT, vbuf, OT);

  // proj + bias + residual
  gemm_nt_k<3><<<dim3(2, 32, 8), 256, 0, stream>>>(wpb, OT, CH, CH, CH,
                                                   d_out, nullptr, b_proj, x);
}

// Round 6
// 362.102 us; speedup vs baseline: 1.1843x; 1.1843x over previous
//
#include <hip/hip_runtime.h>
#include <hip/hip_bf16.h>
#include <stdint.h>

typedef __bf16 bf16_t;
typedef __bf16 bf16x8 __attribute__((ext_vector_type(8)));
typedef __bf16 bf16x4 __attribute__((ext_vector_type(4)));
typedef float f32x4 __attribute__((ext_vector_type(4)));
typedef float f32x16 __attribute__((ext_vector_type(16)));

#define NPIX 4096
#define CH 256

// ---------------- GroupNorm stats (2-stage) ----------------
__global__ __launch_bounds__(256) void gn_partial_k(const float* __restrict__ x,
                                                    float* __restrict__ acc2) {
  int bg = blockIdx.x >> 3;
  int chunk = blockIdx.x & 7;
  const float4* xp = (const float4*)(x + (size_t)bg * 32 * NPIX) + chunk * (32 * NPIX / 4 / 8);
  float s = 0.f, ss = 0.f;
  for (int i = threadIdx.x; i < 32 * NPIX / 4 / 8; i += 256) {
    float4 v = xp[i];
    s  += v.x + v.y + v.z + v.w;
    ss += v.x * v.x + v.y * v.y + v.z * v.z + v.w * v.w;
  }
  int l = threadIdx.x & 63, w = threadIdx.x >> 6;
  #pragma unroll
  for (int off = 32; off; off >>= 1) { s += __shfl_down(s, off); ss += __shfl_down(ss, off); }
  __shared__ float rs[4], rss[4];
  if (l == 0) { rs[w] = s; rss[w] = ss; }
  __syncthreads();
  if (threadIdx.x == 0) {
    atomicAdd(&acc2[bg * 2],     rs[0] + rs[1] + rs[2] + rs[3]);
    atomicAdd(&acc2[bg * 2 + 1], rss[0] + rss[1] + rss[2] + rss[3]);
  }
}

__global__ void gn_finalize_k(const float* __restrict__ acc2, float* __restrict__ stats) {
  int bg = threadIdx.x;  // 64 threads
  float mean = acc2[bg * 2] * (1.f / (32.f * NPIX));
  float var  = acc2[bg * 2 + 1] * (1.f / (32.f * NPIX)) - mean * mean;
  stats[bg * 2]     = mean;
  stats[bg * 2 + 1] = rsqrtf(var + 1e-5f);
}

// ------------- normalize + transpose [b][c][p] -> bf16 [b][p][c] -------------
__global__ __launch_bounds__(256) void gn_apply_t_k(const float* __restrict__ x,
    const float* __restrict__ stats, const float* __restrict__ gamma,
    const float* __restrict__ beta, bf16_t* __restrict__ xnT) {
  __shared__ float tile[32][33];
  int b = blockIdx.z;
  int p0 = blockIdx.x * 32, c0 = blockIdx.y * 32;
  int g = c0 >> 5;
  float mean = stats[(b * 8 + g) * 2], rstd = stats[(b * 8 + g) * 2 + 1];
  int tx = threadIdx.x, ty = threadIdx.y;
  const float* xb = x + ((size_t)b * CH + c0) * NPIX + p0;
  #pragma unroll
  for (int j = 0; j < 4; ++j) {
    int c = ty + j * 8;
    float v = xb[(size_t)c * NPIX + tx];
    tile[c][tx] = (v - mean) * rstd * gamma[c0 + c] + beta[c0 + c];
  }
  __syncthreads();
  bf16_t* op = xnT + ((size_t)b * NPIX + p0) * CH + c0;
  #pragma unroll
  for (int j = 0; j < 4; ++j) {
    int p = ty + j * 8;
    op[(size_t)p * CH + tx] = (bf16_t)tile[tx][p];
  }
}

// ---------------- cast weights to bf16 ----------------
__global__ __launch_bounds__(256) void cast_w_k(const float* __restrict__ wq,
    const float* __restrict__ wp, bf16_t* __restrict__ wqb, bf16_t* __restrict__ wpb) {
  int i = blockIdx.x * 256 + threadIdx.x;
  if (i < 768 * 256) wqb[i] = (bf16_t)wq[i];
  if (i < 256 * 256) wpb[i] = (bf16_t)wp[i];
}

// ---------------- NT GEMM (modes 0,3) ----------------
#define LSTR 80

template <int MODE>
__global__ __launch_bounds__(256) void gemm_nt_k(
    const bf16_t* __restrict__ Ag, const bf16_t* __restrict__ Bg,
    int lda, int ldb, int K,
    void* __restrict__ O0, void* __restrict__ O1,
    const float* __restrict__ bias, const float* __restrict__ resid) {
  __shared__ __align__(16) char ldsA[128 * LSTR];
  __shared__ __align__(16) char ldsB[128 * LSTR];

  const int t = threadIdx.x;
  const int l = t & 63;
  const int w = t >> 6;
  const int wr = w >> 1, wc = w & 1;
  const int bm = blockIdx.x * 128;
  const int bn = blockIdx.y * 128;
  const int bz = blockIdx.z;

  const bf16_t* Ap = Ag;
  const bf16_t* Bp = Bg;
  if constexpr (MODE == 0) Ap += (size_t)bz * NPIX * CH;
  if constexpr (MODE == 3) Bp += (size_t)bz * NPIX * CH;

  f32x4 acc[4][4] = {};

  const int srow = t >> 2;
  const int scol = (t & 3) * 8;

  for (int k0 = 0; k0 < K; k0 += 32) {
    __syncthreads();
    #pragma unroll
    for (int it = 0; it < 2; ++it) {
      int r = it * 64 + srow;
      *(bf16x8*)(ldsA + r * LSTR + scol * 2) =
          *(const bf16x8*)(Ap + (size_t)(bm + r) * lda + k0 + scol);
      *(bf16x8*)(ldsB + r * LSTR + scol * 2) =
          *(const bf16x8*)(Bp + (size_t)(bn + r) * ldb + k0 + scol);
    }
    __syncthreads();
    bf16x8 fa[4], fb[4];
    #pragma unroll
    for (int m = 0; m < 4; ++m)
      fa[m] = *(const bf16x8*)(ldsA + (wr * 64 + m * 16 + (l & 15)) * LSTR + (l >> 4) * 16);
    #pragma unroll
    for (int n = 0; n < 4; ++n)
      fb[n] = *(const bf16x8*)(ldsB + (wc * 64 + n * 16 + (l & 15)) * LSTR + (l >> 4) * 16);
    #pragma unroll
    for (int m = 0; m < 4; ++m)
      #pragma unroll
      for (int n = 0; n < 4; ++n)
        acc[m][n] = __builtin_amdgcn_mfma_f32_16x16x32_bf16(fa[m], fb[n], acc[m][n], 0, 0, 0);
  }

  const int r0 = bm + wr * 64 + (l >> 4) * 4;
  const int c0 = bn + wc * 64 + (l & 15);
  #pragma unroll
  for (int m = 0; m < 4; ++m) {
    #pragma unroll
    for (int n = 0; n < 4; ++n) {
      int col = c0 + n * 16;
      #pragma unroll
      for (int j = 0; j < 4; ++j) {
        int row = r0 + m * 16 + j;
        float v = acc[m][n][j];
        if constexpr (MODE == 0) {
          float val = v + bias[col];
          if (col < 256) val *= 0.09016844006f;  // fold c1=log2e/16 into q
          if (col < 512)
            ((bf16_t*)O0)[(size_t)bz * NPIX * 512 + (size_t)row * 512 + col] = (bf16_t)val;
          else
            ((bf16_t*)O1)[(size_t)bz * CH * NPIX + (size_t)(col - 512) * NPIX + row] = (bf16_t)val;
        } else {
          size_t idx = (size_t)bz * CH * NPIX + (size_t)row * NPIX + col;
          ((float*)O0)[idx] = v + bias[row] + resid[idx];
        }
      }
    }
  }
}

// ---------------- fused flash attention (r4 structure + T5/tree/addr micro-opts) ----
// 512 threads = 8 waves; wave (g,half): q-group g (32 rows), kv-half of KVB=64.
// K,V double-buffered in LDS via global_load_lds (linear dest, XOR-swizzled
// SOURCE addresses; ds_reads apply the same XOR).  ONE barrier per tile:
// stage(t+1)->buf^1 at tile top, compute(t) from buf, barrier at tile end.
#define KVB 64
#define KBYTES 32768   // 64 kv rows * 512 B
#define VBYTES 32768   // 256 c rows * 128 B

__device__ __forceinline__ void dma16(const void* g, void* l) {
  __builtin_amdgcn_global_load_lds(
      (const __attribute__((address_space(1))) unsigned int*)g,
      (__attribute__((address_space(3))) unsigned int*)l, 16, 0, 0);
}

__device__ inline unsigned int pack2bf(float lo, float hi) {
  unsigned short a = __builtin_bit_cast(unsigned short, (bf16_t)lo);
  unsigned short b = __builtin_bit_cast(unsigned short, (bf16_t)hi);
  return (unsigned int)a | ((unsigned int)b << 16);
}

__global__ __launch_bounds__(512, 2) void flash_k(
    const bf16_t* __restrict__ qkT, const bf16_t* __restrict__ vglob,
    bf16_t* __restrict__ OT) {
  __shared__ __align__(16) char kS[2 * KBYTES];
  __shared__ __align__(16) char vS[2 * VBYTES];
  __shared__ float mls[8][2][32];

  const int t = threadIdx.x;
  const int l = t & 63, w = t >> 6;       // w 0..7
  const int lq = l & 31, h = l >> 5;
  const int g = w >> 1, half = w & 1;
  const int batch = blockIdx.x & 7;        // one batch per XCD
  const int q0 = (blockIdx.x >> 3) * 128;

  const bf16_t* qk_b = qkT + (size_t)batch * NPIX * 512;
  const bf16_t* v_b  = vglob + (size_t)batch * CH * NPIX;

  // Q fragments (persistent, pre-scaled by c1): Q[q0+g*32+lq][kk*16 + h*8 +: 8]
  bf16x8 qf[16];
  const bf16_t* qrow = qk_b + (size_t)(q0 + g * 32 + lq) * 512 + h * 8;
  #pragma unroll
  for (int kk = 0; kk < 16; ++kk) qf[kk] = *(const bf16x8*)(qrow + kk * 16);

  // DMA lane geometry (wave-uniform LDS base + lane*16 linear dest)
  const int krow_l = w * 8 + (l >> 5);   // + it*2
  const int kslot  = l & 31;
  const int vrow_l = w * 32 + (l >> 3);  // + it*8
  const int vslot  = l & 7;
  const bf16_t* ksrc = qk_b + 256;

  auto stage = [&](int tile, int buf) {
    #pragma unroll
    for (int it = 0; it < 4; ++it) {
      int r = krow_l + it * 2;
      dma16(ksrc + (size_t)(tile * KVB + r) * 512 + ((kslot ^ (r & 31)) << 3),
            kS + buf * KBYTES + (w * 8 + it * 2) * 512);
      int c = vrow_l + it * 8;
      dma16(v_b + (size_t)c * NPIX + tile * KVB + ((vslot ^ (c & 7)) << 3),
            vS + buf * VBYTES + (w * 32 + it * 8) * 128);
    }
  };

  stage(0, 0);
  __syncthreads();

  f32x16 acc_o[8] = {};
  float m = -1e30f, lsum = 0.f;
  const int krow = half * 32 + lq;
  const char* kbase = kS + krow * 512;
  const int kxor = (h << 4) ^ (lq << 4);                      // ((2kk+h)^lq)<<4 = kxor^(kk<<5)
  const int vxor = (half << 6) ^ (h << 4) ^ ((lq & 7) << 4);  // ((4*half+2*kk2+h)^(lq&7))<<4
  const char* vlane = vS + lq * 128;

  for (int tile = 0; tile < 64; ++tile) {
    const int cur = tile & 1;
    if (tile < 63) stage(tile + 1, cur ^ 1);

    // QK^T (swapped): s = S^T[kv = half*32 + crow(r,h)][q = lq]  (c1 pre-folded in Q)
    f32x16 s = {};
    const char* kb = kbase + cur * KBYTES;
    __builtin_amdgcn_s_setprio(1);
    #pragma unroll
    for (int kk = 0; kk < 16; ++kk) {
      bf16x8 kf = *(const bf16x8*)(kb + (kxor ^ (kk << 5)));
      s = __builtin_amdgcn_mfma_f32_32x32x16_bf16(kf, qf[kk], s, 0, 0, 0);
    }
    __builtin_amdgcn_s_setprio(0);

    // online softmax (log2 domain), tree reductions, defer-max (T13)
    float m0 = fmaxf(s[0], s[1]),   m1 = fmaxf(s[2], s[3]);
    float m2 = fmaxf(s[4], s[5]),   m3 = fmaxf(s[6], s[7]);
    float m4 = fmaxf(s[8], s[9]),   m5 = fmaxf(s[10], s[11]);
    float m6 = fmaxf(s[12], s[13]), m7 = fmaxf(s[14], s[15]);
    m0 = fmaxf(m0, m1); m2 = fmaxf(m2, m3); m4 = fmaxf(m4, m5); m6 = fmaxf(m6, m7);
    float tmax = fmaxf(fmaxf(m0, m2), fmaxf(m4, m6));
    tmax = fmaxf(tmax, __shfl_xor(tmax, 32, 64));
    if (!__all(tmax <= m + 10.f)) {
      float mnew = fmaxf(m, tmax);
      float sc = exp2f(m - mnew);
      m = mnew; lsum *= sc;
      #pragma unroll
      for (int n2 = 0; n2 < 8; ++n2)
        #pragma unroll
        for (int r = 0; r < 16; ++r) acc_o[n2][r] *= sc;
    }
    #pragma unroll
    for (int r = 0; r < 16; ++r) s[r] = exp2f(s[r] - m);
    float a0 = s[0] + s[1],   a1 = s[2] + s[3];
    float a2 = s[4] + s[5],   a3 = s[6] + s[7];
    float a4 = s[8] + s[9],   a5 = s[10] + s[11];
    float a6 = s[12] + s[13], a7 = s[14] + s[15];
    a0 += a1; a2 += a3; a4 += a5; a6 += a7;
    float ls = (a0 + a2) + (a4 + a6);
    ls += __shfl_xor(ls, 32, 64);
    lsum += ls;

    // pack P -> PV A-frags: pa[kk2] = P[q=lq][kv_local = kk2*16 + h*8 +: 8]
    bf16x8 pa[2];
    #pragma unroll
    for (int kk2 = 0; kk2 < 2; ++kk2) {
      const int hi = kk2 * 8;
      unsigned int wkeep[2], wsend[2];
      #pragma unroll
      for (int j = 0; j < 2; ++j) {
        float b0 = s[2 * j + hi],     c0 = s[2 * j + 1 + hi];
        float b1 = s[2 * j + 4 + hi], c1v = s[2 * j + 5 + hi];
        float ka = h ? b1 : b0, kb2 = h ? c1v : c0;
        float sa = h ? b0 : b1, sb = h ? c0 : c1v;
        wkeep[j] = pack2bf(ka, kb2);
        wsend[j] = pack2bf(sa, sb);
      }
      unsigned int wr0 = __shfl_xor(wsend[0], 32, 64);
      unsigned int wr1 = __shfl_xor(wsend[1], 32, 64);
      union { unsigned int u[4]; bf16x8 v; } pu;
      pu.u[0] = h ? wr0 : wkeep[0];
      pu.u[1] = h ? wr1 : wkeep[1];
      pu.u[2] = h ? wkeep[0] : wr0;
      pu.u[3] = h ? wkeep[1] : wr1;
      pa[kk2] = pu.v;
    }

    // PV: acc_o[n2] += P x V[c = n2*32+lq][kv half]
    const char* vb = vlane + cur * VBYTES;
    __builtin_amdgcn_s_setprio(1);
    #pragma unroll
    for (int n2 = 0; n2 < 8; ++n2) {
      const char* vp = vb + n2 * 4096;
      #pragma unroll
      for (int kk2 = 0; kk2 < 2; ++kk2) {
        bf16x8 vf = *(const bf16x8*)(vp + (vxor ^ (kk2 << 5)));
        acc_o[n2] = __builtin_amdgcn_mfma_f32_32x32x16_bf16(pa[kk2], vf, acc_o[n2], 0, 0, 0);
      }
    }
    __builtin_amdgcn_s_setprio(0);
    __syncthreads();
  }

  // ---- merge wave pairs (2g, 2g+1): complementary kv halves ----
  if (h == 0) { mls[w][0][lq] = m; mls[w][1][lq] = lsum; }
  char* abuf = (g < 2) ? (kS + g * 32768) : (vS + (g - 2) * 32768);
  if (half == 1) {
    float* ab = (float*)abuf + l * 128;
    #pragma unroll
    for (int n2 = 0; n2 < 8; ++n2)
      #pragma unroll
      for (int q4 = 0; q4 < 4; ++q4) {
        f32x4 vv;
        vv[0] = acc_o[n2][q4 * 4 + 0]; vv[1] = acc_o[n2][q4 * 4 + 1];
        vv[2] = acc_o[n2][q4 * 4 + 2]; vv[3] = acc_o[n2][q4 * 4 + 3];
        *(f32x4*)(ab + n2 * 16 + q4 * 4) = vv;
      }
  }
  __syncthreads();
  if (half == 0) {
    float mB = mls[w + 1][0][lq], lB = mls[w + 1][1][lq];
    float mS = fmaxf(m, mB);
    float sA = exp2f(m - mS), sB = exp2f(mB - mS);
    float inv = 1.f / (lsum * sA + lB * sB);
    const float* ab = (const float*)abuf + l * 128;
    bf16_t* obase = OT + (size_t)batch * NPIX * CH + (size_t)(q0 + g * 32) * CH + lq;
    #pragma unroll
    for (int r = 0; r < 16; ++r) {
      int q = (r & 3) + 8 * (r >> 2) + 4 * h;
      float sAr = __shfl(sA, q, 64);
      float sBr = __shfl(sB, q, 64);
      float ivr = __shfl(inv, q, 64);
      bf16_t* orow = obase + (size_t)q * CH;
      #pragma unroll
      for (int n2 = 0; n2 < 8; ++n2) {
        float ob = (acc_o[n2][r] * sAr + ab[n2 * 16 + r] * sBr) * ivr;
        orow[n2 * 32] = (bf16_t)ob;
      }
    }
  }
}

extern "C" void kernel_launch(void* const* d_in, const int* in_sizes, int n_in,
                              void* d_out, int out_size, void* d_ws, size_t ws_size,
                              hipStream_t stream) {
  const float* x      = (const float*)d_in[0];
  const float* gamma  = (const float*)d_in[1];
  const float* beta   = (const float*)d_in[2];
  const float* w_qkv  = (const float*)d_in[3];
  const float* b_qkv  = (const float*)d_in[4];
  const float* w_proj = (const float*)d_in[5];
  const float* b_proj = (const float*)d_in[6];

  char* p = (char*)d_ws;
  auto alloc = [&](size_t bytes) {
    char* r = p;
    p += (bytes + 255) & ~(size_t)255;
    return (void*)r;
  };
  bf16_t* qkT  = (bf16_t*)alloc((size_t)8 * NPIX * 512 * 2);  // 32MB  [b][p][q|k]
  bf16_t* vbuf = (bf16_t*)alloc((size_t)8 * CH * NPIX * 2);   // 16MB  [b][c][p]
  bf16_t* OT   = (bf16_t*)alloc((size_t)8 * NPIX * CH * 2);   // 16MB  [b][p][c]
  bf16_t* wqb  = (bf16_t*)alloc(768 * 256 * 2);
  bf16_t* wpb  = (bf16_t*)alloc(256 * 256 * 2);
  float*  acc2 = (float*)alloc(64 * 2 * 4);
  float*  stats= (float*)alloc(64 * 2 * 4);
  bf16_t* xnT  = (bf16_t*)d_out;  // scratch: dead before final proj writes d_out

  hipMemsetAsync(acc2, 0, 64 * 2 * 4, stream);
  gn_partial_k<<<64 * 8, 256, 0, stream>>>(x, acc2);
  gn_finalize_k<<<1, 64, 0, stream>>>(acc2, stats);
  gn_apply_t_k<<<dim3(128, 8, 8), dim3(32, 8), 0, stream>>>(x, stats, gamma, beta, xnT);
  cast_w_k<<<768, 256, 0, stream>>>(w_qkv, w_proj, wqb, wpb);

  // QKV: [p][o] = xnT[p][c] . w_qkv[o][c]  (q pre-scaled by c1 in epilogue)
  gemm_nt_k<0><<<dim3(32, 6, 8), 256, 0, stream>>>(xnT, wqb, CH, CH, CH,
                                                   qkT, vbuf, b_qkv, nullptr);
  // fused attention (all batches): 256 blocks x 512 thr
  flash_k<<<256, 512, 0, stream>>>(qkT, vbuf, OT);

  // proj + bias + residual
  gemm_nt_k<3><<<dim3(2, 32, 8), 256, 0, stream>>>(wpb, OT, CH, CH, CH,
                                                   d_out, nullptr, b_proj, x);
}

// Round 7
// 313.545 us; speedup vs baseline: 1.3677x; 1.1549x over previous
//
#include <hip/hip_runtime.h>
#include <hip/hip_bf16.h>
#include <stdint.h>

typedef __bf16 bf16_t;
typedef __bf16 bf16x8 __attribute__((ext_vector_type(8)));
typedef float f32x4 __attribute__((ext_vector_type(4)));
typedef float f32x16 __attribute__((ext_vector_type(16)));

#define NPIX 4096
#define CH 256

// ---------------- GroupNorm stats (2-stage) ----------------
__global__ __launch_bounds__(256) void gn_partial_k(const float* __restrict__ x,
                                                    float* __restrict__ acc2) {
  int bg = blockIdx.x >> 3;
  int chunk = blockIdx.x & 7;
  const float4* xp = (const float4*)(x + (size_t)bg * 32 * NPIX) + chunk * (32 * NPIX / 4 / 8);
  float s = 0.f, ss = 0.f;
  for (int i = threadIdx.x; i < 32 * NPIX / 4 / 8; i += 256) {
    float4 v = xp[i];
    s  += v.x + v.y + v.z + v.w;
    ss += v.x * v.x + v.y * v.y + v.z * v.z + v.w * v.w;
  }
  int l = threadIdx.x & 63, w = threadIdx.x >> 6;
  #pragma unroll
  for (int off = 32; off; off >>= 1) { s += __shfl_down(s, off); ss += __shfl_down(ss, off); }
  __shared__ float rs[4], rss[4];
  if (l == 0) { rs[w] = s; rss[w] = ss; }
  __syncthreads();
  if (threadIdx.x == 0) {
    atomicAdd(&acc2[bg * 2],     rs[0] + rs[1] + rs[2] + rs[3]);
    atomicAdd(&acc2[bg * 2 + 1], rss[0] + rss[1] + rss[2] + rss[3]);
  }
}

__global__ void gn_finalize_k(const float* __restrict__ acc2, float* __restrict__ stats) {
  int bg = threadIdx.x;  // 64 threads
  float mean = acc2[bg * 2] * (1.f / (32.f * NPIX));
  float var  = acc2[bg * 2 + 1] * (1.f / (32.f * NPIX)) - mean * mean;
  stats[bg * 2]     = mean;
  stats[bg * 2 + 1] = rsqrtf(var + 1e-5f);
}

// ------------- normalize + transpose [b][c][p] -> bf16 [b][p][c] -------------
__global__ __launch_bounds__(256) void gn_apply_t_k(const float* __restrict__ x,
    const float* __restrict__ stats, const float* __restrict__ gamma,
    const float* __restrict__ beta, bf16_t* __restrict__ xnT) {
  __shared__ float tile[32][33];
  int b = blockIdx.z;
  int p0 = blockIdx.x * 32, c0 = blockIdx.y * 32;
  int g = c0 >> 5;
  float mean = stats[(b * 8 + g) * 2], rstd = stats[(b * 8 + g) * 2 + 1];
  int tx = threadIdx.x, ty = threadIdx.y;
  const float* xb = x + ((size_t)b * CH + c0) * NPIX + p0;
  #pragma unroll
  for (int j = 0; j < 4; ++j) {
    int c = ty + j * 8;
    float v = xb[(size_t)c * NPIX + tx];
    tile[c][tx] = (v - mean) * rstd * gamma[c0 + c] + beta[c0 + c];
  }
  __syncthreads();
  bf16_t* op = xnT + ((size_t)b * NPIX + p0) * CH + c0;
  #pragma unroll
  for (int j = 0; j < 4; ++j) {
    int p = ty + j * 8;
    op[(size_t)p * CH + tx] = (bf16_t)tile[tx][p];
  }
}

// ---------------- cast weights to bf16 ----------------
__global__ __launch_bounds__(256) void cast_w_k(const float* __restrict__ wq,
    const float* __restrict__ wp, bf16_t* __restrict__ wqb, bf16_t* __restrict__ wpb) {
  int i = blockIdx.x * 256 + threadIdx.x;
  if (i < 768 * 256) wqb[i] = (bf16_t)wq[i];
  if (i < 256 * 256) wpb[i] = (bf16_t)wp[i];
}

__device__ __forceinline__ unsigned char to_fp8(float v) {
  return (unsigned char)(__builtin_amdgcn_cvt_pk_fp8_f32(v, 0.f, 0, 0) & 0xff);
}

// ---------------- NT GEMM (modes 0,3) ----------------
// MODE 0: out q,k -> qkT fp8 [b][p][512] (q prescaled by c1); v -> vbuf fp8 [b][c][p]
// MODE 3: proj -> d_out fp32 + bias + residual
#define LSTR 80

template <int MODE>
__global__ __launch_bounds__(256) void gemm_nt_k(
    const bf16_t* __restrict__ Ag, const bf16_t* __restrict__ Bg,
    int lda, int ldb, int K,
    void* __restrict__ O0, void* __restrict__ O1,
    const float* __restrict__ bias, const float* __restrict__ resid) {
  __shared__ __align__(16) char ldsA[128 * LSTR];
  __shared__ __align__(16) char ldsB[128 * LSTR];

  const int t = threadIdx.x;
  const int l = t & 63;
  const int w = t >> 6;
  const int wr = w >> 1, wc = w & 1;
  const int bm = blockIdx.x * 128;
  const int bn = blockIdx.y * 128;
  const int bz = blockIdx.z;

  const bf16_t* Ap = Ag;
  const bf16_t* Bp = Bg;
  if constexpr (MODE == 0) Ap += (size_t)bz * NPIX * CH;
  if constexpr (MODE == 3) Bp += (size_t)bz * NPIX * CH;

  f32x4 acc[4][4] = {};

  const int srow = t >> 2;
  const int scol = (t & 3) * 8;

  for (int k0 = 0; k0 < K; k0 += 32) {
    __syncthreads();
    #pragma unroll
    for (int it = 0; it < 2; ++it) {
      int r = it * 64 + srow;
      *(bf16x8*)(ldsA + r * LSTR + scol * 2) =
          *(const bf16x8*)(Ap + (size_t)(bm + r) * lda + k0 + scol);
      *(bf16x8*)(ldsB + r * LSTR + scol * 2) =
          *(const bf16x8*)(Bp + (size_t)(bn + r) * ldb + k0 + scol);
    }
    __syncthreads();
    bf16x8 fa[4], fb[4];
    #pragma unroll
    for (int m = 0; m < 4; ++m)
      fa[m] = *(const bf16x8*)(ldsA + (wr * 64 + m * 16 + (l & 15)) * LSTR + (l >> 4) * 16);
    #pragma unroll
    for (int n = 0; n < 4; ++n)
      fb[n] = *(const bf16x8*)(ldsB + (wc * 64 + n * 16 + (l & 15)) * LSTR + (l >> 4) * 16);
    #pragma unroll
    for (int m = 0; m < 4; ++m)
      #pragma unroll
      for (int n = 0; n < 4; ++n)
        acc[m][n] = __builtin_amdgcn_mfma_f32_16x16x32_bf16(fa[m], fb[n], acc[m][n], 0, 0, 0);
  }

  const int r0 = bm + wr * 64 + (l >> 4) * 4;
  const int c0 = bn + wc * 64 + (l & 15);
  #pragma unroll
  for (int m = 0; m < 4; ++m) {
    #pragma unroll
    for (int n = 0; n < 4; ++n) {
      int col = c0 + n * 16;
      #pragma unroll
      for (int j = 0; j < 4; ++j) {
        int row = r0 + m * 16 + j;
        float v = acc[m][n][j];
        if constexpr (MODE == 0) {
          float val = v + bias[col];
          if (col < 256) val *= 0.09016844006f;  // fold c1=log2e/16 into q
          if (col < 512)
            ((unsigned char*)O0)[(size_t)bz * NPIX * 512 + (size_t)row * 512 + col] = to_fp8(val);
          else
            ((unsigned char*)O1)[(size_t)bz * CH * NPIX + (size_t)(col - 512) * NPIX + row] = to_fp8(val);
        } else {
          size_t idx = (size_t)bz * CH * NPIX + (size_t)row * NPIX + col;
          ((float*)O0)[idx] = v + bias[row] + resid[idx];
        }
      }
    }
  }
}

// ---------------- fused flash attention (fp8 QKV/P, 4-wave blocks) ----------------
// 256 threads = 4 waves; wave (g,half): q-group g (32 rows, Q-tile 64), kv-half
// of KVB=64. fp8 e4m3 everywhere on the MFMA inputs; fp32 softmax state.
// K,V double-buffered LDS (16KB tiles) via global_load_lds, XOR-swizzled source,
// same XOR on ds_reads. 65KB LDS -> 2 blocks/CU -> phase-diverse overlap.
#define KVB 64
#define KB8 16384   // 64 kv rows * 256 B
#define VB8 16384   // 256 c rows * 64 B

__device__ __forceinline__ void dma16(const void* g, void* l) {
  __builtin_amdgcn_global_load_lds(
      (const __attribute__((address_space(1))) unsigned int*)g,
      (__attribute__((address_space(3))) unsigned int*)l, 16, 0, 0);
}

__device__ __forceinline__ unsigned int pk4(float a, float b, float c, float d) {
  int r = __builtin_amdgcn_cvt_pk_fp8_f32(a, b, 0, 0);
  r = __builtin_amdgcn_cvt_pk_fp8_f32(c, d, r, 1);
  return (unsigned int)r;
}

__global__ __launch_bounds__(256, 2) void flash_k(
    const unsigned char* __restrict__ qkT, const unsigned char* __restrict__ vglob,
    bf16_t* __restrict__ OT) {
  __shared__ __align__(16) char kS[2 * KB8];
  __shared__ __align__(16) char vS[2 * VB8];
  __shared__ float mls[4][2][32];

  const int t = threadIdx.x;
  const int l = t & 63, w = t >> 6;       // w 0..3
  const int lq = l & 31, h = l >> 5;
  const int g = w >> 1, half = w & 1;
  const int batch = blockIdx.x & 7;        // batch per XCD (L2-resident K/V)
  const int q0 = (blockIdx.x >> 3) * 64;

  const unsigned char* qk_b = qkT + (size_t)batch * NPIX * 512;
  const unsigned char* v_b  = vglob + (size_t)batch * CH * NPIX;

  // Q fragments fp8 (persistent, prescaled): lane holds Q[q0+g*32+lq][kk*16+h*8 +:8]
  unsigned long qf[16];
  const unsigned char* qrow = qk_b + (size_t)(q0 + g * 32 + lq) * 512 + h * 8;
  #pragma unroll
  for (int kk = 0; kk < 16; ++kk) qf[kk] = *(const unsigned long*)(qrow + kk * 16);

  // DMA lane geometry: K row 256B (16 chunks of 16B), V row 64B (4 chunks)
  const int kRowL = t >> 4;                      // + it*16
  const int kChunk0 = (t & 15) ^ (t >> 4);       // ^ ((it&1)<<3)
  const int vRowL = t >> 2;                      // + it*64
  const int vChunk = ((t & 3) ^ ((t >> 3) & 3)) << 4;
  const unsigned char* ksrc = qk_b + 256;

  auto stage = [&](int tile, int buf) {
    #pragma unroll
    for (int it = 0; it < 4; ++it) {
      int kr = it * 16 + kRowL;
      dma16(ksrc + (size_t)(tile * KVB + kr) * 512 + ((kChunk0 ^ ((it & 1) << 3)) << 4),
            kS + buf * KB8 + it * 4096 + w * 1024);
      int vr = it * 64 + vRowL;
      dma16(v_b + (size_t)vr * NPIX + tile * KVB + vChunk,
            vS + buf * VB8 + it * 4096 + w * 1024);
    }
  };

  stage(0, 0);
  __syncthreads();

  f32x16 acc_o[8] = {};
  float m = -1e30f, lsum = 0.f;
  const int krow = half * 32 + lq;
  const char* kbase = kS + krow * 256;
  const int koff = (h << 3) | (((lq & 15) ^ ((lq >> 4) << 3)) << 4);
  const int vxor = (h << 3) | ((((half << 1) ^ ((lq >> 1) & 3))) << 4);
  const char* vlane = vS + lq * 64;

  for (int tile = 0; tile < 64; ++tile) {
    const int cur = tile & 1;
    if (tile < 63) stage(tile + 1, cur ^ 1);

    // QK^T (swapped, fp8): s = S^T[kv = half*32 + crow(r,h)][q = lq]
    f32x16 s = {};
    const char* kb = kbase + cur * KB8;
    __builtin_amdgcn_s_setprio(1);
    #pragma unroll
    for (int kk = 0; kk < 16; ++kk) {
      long kf = *(const long*)(kb + (koff ^ (kk << 4)));
      s = __builtin_amdgcn_mfma_f32_32x32x16_fp8_fp8(kf, (long)qf[kk], s, 0, 0, 0);
    }
    __builtin_amdgcn_s_setprio(0);

    // online softmax (log2 domain), tree reductions, defer-max THR=8 (P<=256<448)
    float m0 = fmaxf(s[0], s[1]),   m1 = fmaxf(s[2], s[3]);
    float m2 = fmaxf(s[4], s[5]),   m3 = fmaxf(s[6], s[7]);
    float m4 = fmaxf(s[8], s[9]),   m5 = fmaxf(s[10], s[11]);
    float m6 = fmaxf(s[12], s[13]), m7 = fmaxf(s[14], s[15]);
    m0 = fmaxf(m0, m1); m2 = fmaxf(m2, m3); m4 = fmaxf(m4, m5); m6 = fmaxf(m6, m7);
    float tmax = fmaxf(fmaxf(m0, m2), fmaxf(m4, m6));
    tmax = fmaxf(tmax, __shfl_xor(tmax, 32, 64));
    if (!__all(tmax <= m + 8.f)) {
      float mnew = fmaxf(m, tmax);
      float sc = exp2f(m - mnew);
      m = mnew; lsum *= sc;
      #pragma unroll
      for (int n2 = 0; n2 < 8; ++n2)
        #pragma unroll
        for (int r = 0; r < 16; ++r) acc_o[n2][r] *= sc;
    }
    #pragma unroll
    for (int r = 0; r < 16; ++r) s[r] = exp2f(s[r] - m);
    float a0 = s[0] + s[1],   a1 = s[2] + s[3];
    float a2 = s[4] + s[5],   a3 = s[6] + s[7];
    float a4 = s[8] + s[9],   a5 = s[10] + s[11];
    float a6 = s[12] + s[13], a7 = s[14] + s[15];
    a0 += a1; a2 += a3; a4 += a5; a6 += a7;
    float ls = (a0 + a2) + (a4 + a6);
    ls += __shfl_xor(ls, 32, 64);
    lsum += ls;

    // pack P -> fp8 A-frags: pa[kk2] = P[q=lq][kv_local = kk2*16 + h*8 +: 8]
    unsigned long pa[2];
    #pragma unroll
    for (int kk2 = 0; kk2 < 2; ++kk2) {
      const int hi = kk2 * 8;
      unsigned int own_lo = pk4(s[hi + 0], s[hi + 1], s[hi + 2], s[hi + 3]);
      unsigned int own_hi = pk4(s[hi + 4], s[hi + 5], s[hi + 6], s[hi + 7]);
      unsigned int keep = h ? own_hi : own_lo;
      unsigned int send = h ? own_lo : own_hi;
      unsigned int recv = __shfl_xor(send, 32, 64);
      unsigned int lo32 = h ? recv : keep;
      unsigned int hi32 = h ? keep : recv;
      pa[kk2] = ((unsigned long)hi32 << 32) | lo32;
    }

    // PV (fp8): acc_o[n2] += P x V[c = n2*32+lq][kv half]
    const char* vb = vlane + cur * VB8;
    __builtin_amdgcn_s_setprio(1);
    #pragma unroll
    for (int n2 = 0; n2 < 8; ++n2) {
      const char* vp = vb + n2 * 2048;
      #pragma unroll
      for (int kk2 = 0; kk2 < 2; ++kk2) {
        long vf = *(const long*)(vp + (vxor ^ (kk2 << 4)));
        acc_o[n2] = __builtin_amdgcn_mfma_f32_32x32x16_fp8_fp8((long)pa[kk2], vf, acc_o[n2], 0, 0, 0);
      }
    }
    __builtin_amdgcn_s_setprio(0);
    __syncthreads();
  }

  // ---- merge wave pairs (2g, 2g+1): complementary kv halves ----
  if (h == 0) { mls[w][0][lq] = m; mls[w][1][lq] = lsum; }
  char* abuf = g == 0 ? kS : vS;
  if (half == 1) {
    float* ab = (float*)abuf + l * 128;
    #pragma unroll
    for (int n2 = 0; n2 < 8; ++n2)
      #pragma unroll
      for (int q4 = 0; q4 < 4; ++q4) {
        f32x4 vv;
        vv[0] = acc_o[n2][q4 * 4 + 0]; vv[1] = acc_o[n2][q4 * 4 + 1];
        vv[2] = acc_o[n2][q4 * 4 + 2]; vv[3] = acc_o[n2][q4 * 4 + 3];
        *(f32x4*)(ab + n2 * 16 + q4 * 4) = vv;
      }
  }
  __syncthreads();
  if (half == 0) {
    float mB = mls[w + 1][0][lq], lB = mls[w + 1][1][lq];
    float mS = fmaxf(m, mB);
    float sA = exp2f(m - mS), sB = exp2f(mB - mS);
    float inv = 1.f / (lsum * sA + lB * sB);
    const float* ab = (const float*)abuf + l * 128;
    bf16_t* obase = OT + (size_t)batch * NPIX * CH + (size_t)(q0 + g * 32) * CH + lq;
    #pragma unroll
    for (int r = 0; r < 16; ++r) {
      int q = (r & 3) + 8 * (r >> 2) + 4 * h;
      float sAr = __shfl(sA, q, 64);
      float sBr = __shfl(sB, q, 64);
      float ivr = __shfl(inv, q, 64);
      bf16_t* orow = obase + (size_t)q * CH;
      #pragma unroll
      for (int n2 = 0; n2 < 8; ++n2) {
        float ob = (acc_o[n2][r] * sAr + ab[n2 * 16 + r] * sBr) * ivr;
        orow[n2 * 32] = (bf16_t)ob;
      }
    }
  }
}

extern "C" void kernel_launch(void* const* d_in, const int* in_sizes, int n_in,
                              void* d_out, int out_size, void* d_ws, size_t ws_size,
                              hipStream_t stream) {
  const float* x      = (const float*)d_in[0];
  const float* gamma  = (const float*)d_in[1];
  const float* beta   = (const float*)d_in[2];
  const float* w_qkv  = (const float*)d_in[3];
  const float* b_qkv  = (const float*)d_in[4];
  const float* w_proj = (const float*)d_in[5];
  const float* b_proj = (const float*)d_in[6];

  char* p = (char*)d_ws;
  auto alloc = [&](size_t bytes) {
    char* r = p;
    p += (bytes + 255) & ~(size_t)255;
    return (void*)r;
  };
  unsigned char* qkT  = (unsigned char*)alloc((size_t)8 * NPIX * 512);  // 16MB fp8 [b][p][q|k]
  unsigned char* vbuf = (unsigned char*)alloc((size_t)8 * CH * NPIX);   // 8MB  fp8 [b][c][p]
  bf16_t* OT   = (bf16_t*)alloc((size_t)8 * NPIX * CH * 2);             // 16MB bf16 [b][p][c]
  bf16_t* wqb  = (bf16_t*)alloc(768 * 256 * 2);
  bf16_t* wpb  = (bf16_t*)alloc(256 * 256 * 2);
  float*  acc2 = (float*)alloc(64 * 2 * 4);
  float*  stats= (float*)alloc(64 * 2 * 4);
  bf16_t* xnT  = (bf16_t*)d_out;  // scratch: dead before final proj writes d_out

  hipMemsetAsync(acc2, 0, 64 * 2 * 4, stream);
  gn_partial_k<<<64 * 8, 256, 0, stream>>>(x, acc2);
  gn_finalize_k<<<1, 64, 0, stream>>>(acc2, stats);
  gn_apply_t_k<<<dim3(128, 8, 8), dim3(32, 8), 0, stream>>>(x, stats, gamma, beta, xnT);
  cast_w_k<<<768, 256, 0, stream>>>(w_qkv, w_proj, wqb, wpb);

  // QKV: [p][o] = xnT[p][c] . w_qkv[o][c]  -> fp8 q(prescaled)|k and v
  gemm_nt_k<0><<<dim3(32, 6, 8), 256, 0, stream>>>(xnT, wqb, CH, CH, CH,
                                                   qkT, vbuf, b_qkv, nullptr);
  // fused attention: 512 blocks x 256 thr (4 waves), 2 blocks/CU
  flash_k<<<512, 256, 0, stream>>>(qkT, vbuf, OT);

  // proj + bias + residual
  gemm_nt_k<3><<<dim3(2, 32, 8), 256, 0, stream>>>(wpb, OT, CH, CH, CH,
                                                   d_out, nullptr, b_proj, x);
}

// Round 8
// 299.553 us; speedup vs baseline: 1.4316x; 1.0467x over previous
//
#include <hip/hip_runtime.h>
#include <hip/hip_bf16.h>
#include <stdint.h>

typedef __bf16 bf16_t;
typedef __bf16 bf16x8 __attribute__((ext_vector_type(8)));
typedef float f32x4 __attribute__((ext_vector_type(4)));
typedef float f32x16 __attribute__((ext_vector_type(16)));
typedef int i32x8 __attribute__((ext_vector_type(8)));

#define NPIX 4096
#define CH 256

// ---------------- GroupNorm stats (2-stage) ----------------
__global__ __launch_bounds__(256) void gn_partial_k(const float* __restrict__ x,
                                                    float* __restrict__ acc2) {
  int bg = blockIdx.x >> 3;
  int chunk = blockIdx.x & 7;
  const float4* xp = (const float4*)(x + (size_t)bg * 32 * NPIX) + chunk * (32 * NPIX / 4 / 8);
  float s = 0.f, ss = 0.f;
  for (int i = threadIdx.x; i < 32 * NPIX / 4 / 8; i += 256) {
    float4 v = xp[i];
    s  += v.x + v.y + v.z + v.w;
    ss += v.x * v.x + v.y * v.y + v.z * v.z + v.w * v.w;
  }
  int l = threadIdx.x & 63, w = threadIdx.x >> 6;
  #pragma unroll
  for (int off = 32; off; off >>= 1) { s += __shfl_down(s, off); ss += __shfl_down(ss, off); }
  __shared__ float rs[4], rss[4];
  if (l == 0) { rs[w] = s; rss[w] = ss; }
  __syncthreads();
  if (threadIdx.x == 0) {
    atomicAdd(&acc2[bg * 2],     rs[0] + rs[1] + rs[2] + rs[3]);
    atomicAdd(&acc2[bg * 2 + 1], rss[0] + rss[1] + rss[2] + rss[3]);
  }
}

__global__ void gn_finalize_k(const float* __restrict__ acc2, float* __restrict__ stats) {
  int bg = threadIdx.x;  // 64 threads
  float mean = acc2[bg * 2] * (1.f / (32.f * NPIX));
  float var  = acc2[bg * 2 + 1] * (1.f / (32.f * NPIX)) - mean * mean;
  stats[bg * 2]     = mean;
  stats[bg * 2 + 1] = rsqrtf(var + 1e-5f);
}

// ------------- normalize + transpose [b][c][p] -> bf16 [b][p][c] -------------
__global__ __launch_bounds__(256) void gn_apply_t_k(const float* __restrict__ x,
    const float* __restrict__ stats, const float* __restrict__ gamma,
    const float* __restrict__ beta, bf16_t* __restrict__ xnT) {
  __shared__ float tile[32][33];
  int b = blockIdx.z;
  int p0 = blockIdx.x * 32, c0 = blockIdx.y * 32;
  int g = c0 >> 5;
  float mean = stats[(b * 8 + g) * 2], rstd = stats[(b * 8 + g) * 2 + 1];
  int tx = threadIdx.x, ty = threadIdx.y;
  const float* xb = x + ((size_t)b * CH + c0) * NPIX + p0;
  #pragma unroll
  for (int j = 0; j < 4; ++j) {
    int c = ty + j * 8;
    float v = xb[(size_t)c * NPIX + tx];
    tile[c][tx] = (v - mean) * rstd * gamma[c0 + c] + beta[c0 + c];
  }
  __syncthreads();
  bf16_t* op = xnT + ((size_t)b * NPIX + p0) * CH + c0;
  #pragma unroll
  for (int j = 0; j < 4; ++j) {
    int p = ty + j * 8;
    op[(size_t)p * CH + tx] = (bf16_t)tile[tx][p];
  }
}

// ---------------- cast weights to bf16 ----------------
__global__ __launch_bounds__(256) void cast_w_k(const float* __restrict__ wq,
    const float* __restrict__ wp, bf16_t* __restrict__ wqb, bf16_t* __restrict__ wpb) {
  int i = blockIdx.x * 256 + threadIdx.x;
  if (i < 768 * 256) wqb[i] = (bf16_t)wq[i];
  if (i < 256 * 256) wpb[i] = (bf16_t)wp[i];
}

__device__ __forceinline__ unsigned char to_fp8(float v) {
  return (unsigned char)(__builtin_amdgcn_cvt_pk_fp8_f32(v, 0.f, 0, 0) & 0xff);
}

// ---------------- NT GEMM (modes 0,3) ----------------
// MODE 0: out q,k -> qkT fp8 [b][p][512] (q prescaled by c1); v -> vbuf fp8 [b][c][p]
// MODE 3: proj -> d_out fp32 + bias + residual
#define LSTR 80

template <int MODE>
__global__ __launch_bounds__(256) void gemm_nt_k(
    const bf16_t* __restrict__ Ag, const bf16_t* __restrict__ Bg,
    int lda, int ldb, int K,
    void* __restrict__ O0, void* __restrict__ O1,
    const float* __restrict__ bias, const float* __restrict__ resid) {
  __shared__ __align__(16) char ldsA[128 * LSTR];
  __shared__ __align__(16) char ldsB[128 * LSTR];

  const int t = threadIdx.x;
  const int l = t & 63;
  const int w = t >> 6;
  const int wr = w >> 1, wc = w & 1;
  const int bm = blockIdx.x * 128;
  const int bn = blockIdx.y * 128;
  const int bz = blockIdx.z;

  const bf16_t* Ap = Ag;
  const bf16_t* Bp = Bg;
  if constexpr (MODE == 0) Ap += (size_t)bz * NPIX * CH;
  if constexpr (MODE == 3) Bp += (size_t)bz * NPIX * CH;

  f32x4 acc[4][4] = {};

  const int srow = t >> 2;
  const int scol = (t & 3) * 8;

  for (int k0 = 0; k0 < K; k0 += 32) {
    __syncthreads();
    #pragma unroll
    for (int it = 0; it < 2; ++it) {
      int r = it * 64 + srow;
      *(bf16x8*)(ldsA + r * LSTR + scol * 2) =
          *(const bf16x8*)(Ap + (size_t)(bm + r) * lda + k0 + scol);
      *(bf16x8*)(ldsB + r * LSTR + scol * 2) =
          *(const bf16x8*)(Bp + (size_t)(bn + r) * ldb + k0 + scol);
    }
    __syncthreads();
    bf16x8 fa[4], fb[4];
    #pragma unroll
    for (int m = 0; m < 4; ++m)
      fa[m] = *(const bf16x8*)(ldsA + (wr * 64 + m * 16 + (l & 15)) * LSTR + (l >> 4) * 16);
    #pragma unroll
    for (int n = 0; n < 4; ++n)
      fb[n] = *(const bf16x8*)(ldsB + (wc * 64 + n * 16 + (l & 15)) * LSTR + (l >> 4) * 16);
    #pragma unroll
    for (int m = 0; m < 4; ++m)
      #pragma unroll
      for (int n = 0; n < 4; ++n)
        acc[m][n] = __builtin_amdgcn_mfma_f32_16x16x32_bf16(fa[m], fb[n], acc[m][n], 0, 0, 0);
  }

  const int r0 = bm + wr * 64 + (l >> 4) * 4;
  const int c0 = bn + wc * 64 + (l & 15);
  #pragma unroll
  for (int m = 0; m < 4; ++m) {
    #pragma unroll
    for (int n = 0; n < 4; ++n) {
      int col = c0 + n * 16;
      #pragma unroll
      for (int j = 0; j < 4; ++j) {
        int row = r0 + m * 16 + j;
        float v = acc[m][n][j];
        if constexpr (MODE == 0) {
          float val = v + bias[col];
          if (col < 256) val *= 0.09016844006f;  // fold c1=log2e/16 into q
          if (col < 512)
            ((unsigned char*)O0)[(size_t)bz * NPIX * 512 + (size_t)row * 512 + col] = to_fp8(val);
          else
            ((unsigned char*)O1)[(size_t)bz * CH * NPIX + (size_t)(col - 512) * NPIX + row] = to_fp8(val);
        } else {
          size_t idx = (size_t)bz * CH * NPIX + (size_t)row * NPIX + col;
          ((float*)O0)[idx] = v + bias[row] + resid[idx];
        }
      }
    }
  }
}

// ---------------- fused flash attention (fp8; QK via mfma_scale K=64) ----------------
// 256 threads = 4 waves; wave (g,half): q-group g (32 rows, Q-tile 64), kv-half
// of KVB=64. QK^T: 4x mfma_scale_32x32x64_f8f6f4 (unit scales) per tile;
// PV: 16x mfma_32x32x16_fp8. K,V double-buffered LDS via global_load_lds,
// XOR-swizzled source (16B chunks), same XOR on ds_read_b128.
#define KVB 64
#define KB8 16384   // 64 kv rows * 256 B
#define VB8 16384   // 256 c rows * 64 B

__device__ __forceinline__ void dma16(const void* g, void* l) {
  __builtin_amdgcn_global_load_lds(
      (const __attribute__((address_space(1))) unsigned int*)g,
      (__attribute__((address_space(3))) unsigned int*)l, 16, 0, 0);
}

__device__ __forceinline__ unsigned int pk4(float a, float b, float c, float d) {
  int r = __builtin_amdgcn_cvt_pk_fp8_f32(a, b, 0, 0);
  r = __builtin_amdgcn_cvt_pk_fp8_f32(c, d, r, 1);
  return (unsigned int)r;
}

__global__ __launch_bounds__(256, 2) void flash_k(
    const unsigned char* __restrict__ qkT, const unsigned char* __restrict__ vglob,
    bf16_t* __restrict__ OT) {
  __shared__ __align__(16) char kS[2 * KB8];
  __shared__ __align__(16) char vS[2 * VB8];
  __shared__ float mls[4][2][32];

  const int t = threadIdx.x;
  const int l = t & 63, w = t >> 6;       // w 0..3
  const int lq = l & 31, h = l >> 5;
  const int g = w >> 1, half = w & 1;
  const int batch = blockIdx.x & 7;        // batch per XCD (L2-resident K/V)
  const int q0 = (blockIdx.x >> 3) * 64;

  const unsigned char* qk_b = qkT + (size_t)batch * NPIX * 512;
  const unsigned char* v_b  = vglob + (size_t)batch * CH * NPIX;

  // Q fragments fp8 for K=64 MFMA: lane holds Q[q0+g*32+lq][kk*64 + h*32 +: 32]
  i32x8 qf[4];
  const unsigned char* qrow = qk_b + (size_t)(q0 + g * 32 + lq) * 512 + h * 32;
  #pragma unroll
  for (int kk = 0; kk < 4; ++kk) qf[kk] = *(const i32x8*)(qrow + kk * 64);

  // DMA lane geometry: K row 256B (16 chunks of 16B), V row 64B (4 chunks)
  const int kRowL = t >> 4;                      // + it*16
  const int kChunk0 = (t & 15) ^ (t >> 4);       // ^ ((it&1)<<3)
  const int vRowL = t >> 2;                      // + it*64
  const int vChunk = ((t & 3) ^ ((t >> 3) & 3)) << 4;
  const unsigned char* ksrc = qk_b + 256;

  auto stage = [&](int tile, int buf) {
    #pragma unroll
    for (int it = 0; it < 4; ++it) {
      int kr = it * 16 + kRowL;
      dma16(ksrc + (size_t)(tile * KVB + kr) * 512 + ((kChunk0 ^ ((it & 1) << 3)) << 4),
            kS + buf * KB8 + it * 4096 + w * 1024);
      int vr = it * 64 + vRowL;
      dma16(v_b + (size_t)vr * NPIX + tile * KVB + vChunk,
            vS + buf * VB8 + it * 4096 + w * 1024);
    }
  };

  stage(0, 0);
  __syncthreads();

  f32x16 acc_o[8] = {};
  float m = -1e30f, lsum = 0.f;
  const int krow = half * 32 + lq;
  const char* kbase = kS + krow * 256;
  const int sXor = (lq & 15) ^ ((lq >> 4) << 3);              // chunk swizzle for row krow
  const int vxor = (h << 3) | ((((half << 1) ^ ((lq >> 1) & 3))) << 4);
  const char* vlane = vS + lq * 64;

  for (int tile = 0; tile < 64; ++tile) {
    const int cur = tile & 1;
    if (tile < 63) stage(tile + 1, cur ^ 1);

    // QK^T (swapped, K=64 scaled-fp8, unit scales): s = S^T[kv][q=lq]
    f32x16 s = {};
    const char* kb = kbase + cur * KB8;
    __builtin_amdgcn_s_setprio(1);
    #pragma unroll
    for (int kk = 0; kk < 4; ++kk) {
      const int c0 = kk * 4 + h * 2;
      int4 klo = *(const int4*)(kb + (((c0    ) ^ sXor) << 4));
      int4 khi = *(const int4*)(kb + (((c0 + 1) ^ sXor) << 4));
      i32x8 kf;
      kf[0] = klo.x; kf[1] = klo.y; kf[2] = klo.z; kf[3] = klo.w;
      kf[4] = khi.x; kf[5] = khi.y; kf[6] = khi.z; kf[7] = khi.w;
      s = __builtin_amdgcn_mfma_scale_f32_32x32x64_f8f6f4(kf, qf[kk], s,
                                                          0, 0, 0, 127, 0, 127);
    }
    __builtin_amdgcn_s_setprio(0);

    // online softmax (log2 domain), tree reductions, defer-max THR=8 (P<=256<448)
    float m0 = fmaxf(s[0], s[1]),   m1 = fmaxf(s[2], s[3]);
    float m2 = fmaxf(s[4], s[5]),   m3 = fmaxf(s[6], s[7]);
    float m4 = fmaxf(s[8], s[9]),   m5 = fmaxf(s[10], s[11]);
    float m6 = fmaxf(s[12], s[13]), m7 = fmaxf(s[14], s[15]);
    m0 = fmaxf(m0, m1); m2 = fmaxf(m2, m3); m4 = fmaxf(m4, m5); m6 = fmaxf(m6, m7);
    float tmax = fmaxf(fmaxf(m0, m2), fmaxf(m4, m6));
    tmax = fmaxf(tmax, __shfl_xor(tmax, 32, 64));
    if (!__all(tmax <= m + 8.f)) {
      float mnew = fmaxf(m, tmax);
      float sc = exp2f(m - mnew);
      m = mnew; lsum *= sc;
      #pragma unroll
      for (int n2 = 0; n2 < 8; ++n2)
        #pragma unroll
        for (int r = 0; r < 16; ++r) acc_o[n2][r] *= sc;
    }
    #pragma unroll
    for (int r = 0; r < 16; ++r) s[r] = exp2f(s[r] - m);
    float a0 = s[0] + s[1],   a1 = s[2] + s[3];
    float a2 = s[4] + s[5],   a3 = s[6] + s[7];
    float a4 = s[8] + s[9],   a5 = s[10] + s[11];
    float a6 = s[12] + s[13], a7 = s[14] + s[15];
    a0 += a1; a2 += a3; a4 += a5; a6 += a7;
    float ls = (a0 + a2) + (a4 + a6);
    ls += __shfl_xor(ls, 32, 64);
    lsum += ls;

    // pack P -> fp8 A-frags: pa[kk2] = P[q=lq][kv_local = kk2*16 + h*8 +: 8]
    unsigned long pa[2];
    #pragma unroll
    for (int kk2 = 0; kk2 < 2; ++kk2) {
      const int hi = kk2 * 8;
      unsigned int own_lo = pk4(s[hi + 0], s[hi + 1], s[hi + 2], s[hi + 3]);
      unsigned int own_hi = pk4(s[hi + 4], s[hi + 5], s[hi + 6], s[hi + 7]);
      unsigned int keep = h ? own_hi : own_lo;
      unsigned int send = h ? own_lo : own_hi;
      unsigned int recv = __shfl_xor(send, 32, 64);
      unsigned int lo32 = h ? recv : keep;
      unsigned int hi32 = h ? keep : recv;
      pa[kk2] = ((unsigned long)hi32 << 32) | lo32;
    }

    // PV (fp8 K=16): acc_o[n2] += P x V[c = n2*32+lq][kv half]
    const char* vb = vlane + cur * VB8;
    __builtin_amdgcn_s_setprio(1);
    #pragma unroll
    for (int n2 = 0; n2 < 8; ++n2) {
      const char* vp = vb + n2 * 2048;
      #pragma unroll
      for (int kk2 = 0; kk2 < 2; ++kk2) {
        long vf = *(const long*)(vp + (vxor ^ (kk2 << 4)));
        acc_o[n2] = __builtin_amdgcn_mfma_f32_32x32x16_fp8_fp8((long)pa[kk2], vf, acc_o[n2], 0, 0, 0);
      }
    }
    __builtin_amdgcn_s_setprio(0);
    __syncthreads();
  }

  // ---- merge wave pairs (2g, 2g+1): complementary kv halves ----
  if (h == 0) { mls[w][0][lq] = m; mls[w][1][lq] = lsum; }
  char* abuf = g == 0 ? kS : vS;
  if (half == 1) {
    float* ab = (float*)abuf + l * 128;
    #pragma unroll
    for (int n2 = 0; n2 < 8; ++n2)
      #pragma unroll
      for (int q4 = 0; q4 < 4; ++q4) {
        f32x4 vv;
        vv[0] = acc_o[n2][q4 * 4 + 0]; vv[1] = acc_o[n2][q4 * 4 + 1];
        vv[2] = acc_o[n2][q4 * 4 + 2]; vv[3] = acc_o[n2][q4 * 4 + 3];
        *(f32x4*)(ab + n2 * 16 + q4 * 4) = vv;
      }
  }
  __syncthreads();
  if (half == 0) {
    float mB = mls[w + 1][0][lq], lB = mls[w + 1][1][lq];
    float mS = fmaxf(m, mB);
    float sA = exp2f(m - mS), sB = exp2f(mB - mS);
    float inv = 1.f / (lsum * sA + lB * sB);
    const float* ab = (const float*)abuf + l * 128;
    bf16_t* obase = OT + (size_t)batch * NPIX * CH + (size_t)(q0 + g * 32) * CH + lq;
    #pragma unroll
    for (int r = 0; r < 16; ++r) {
      int q = (r & 3) + 8 * (r >> 2) + 4 * h;
      float sAr = __shfl(sA, q, 64);
      float sBr = __shfl(sB, q, 64);
      float ivr = __shfl(inv, q, 64);
      bf16_t* orow = obase + (size_t)q * CH;
      #pragma unroll
      for (int n2 = 0; n2 < 8; ++n2) {
        float ob = (acc_o[n2][r] * sAr + ab[n2 * 16 + r] * sBr) * ivr;
        orow[n2 * 32] = (bf16_t)ob;
      }
    }
  }
}

extern "C" void kernel_launch(void* const* d_in, const int* in_sizes, int n_in,
                              void* d_out, int out_size, void* d_ws, size_t ws_size,
                              hipStream_t stream) {
  const float* x      = (const float*)d_in[0];
  const float* gamma  = (const float*)d_in[1];
  const float* beta   = (const float*)d_in[2];
  const float* w_qkv  = (const float*)d_in[3];
  const float* b_qkv  = (const float*)d_in[4];
  const float* w_proj = (const float*)d_in[5];
  const float* b_proj = (const float*)d_in[6];

  char* p = (char*)d_ws;
  auto alloc = [&](size_t bytes) {
    char* r = p;
    p += (bytes + 255) & ~(size_t)255;
    return (void*)r;
  };
  unsigned char* qkT  = (unsigned char*)alloc((size_t)8 * NPIX * 512);  // 16MB fp8 [b][p][q|k]
  unsigned char* vbuf = (unsigned char*)alloc((size_t)8 * CH * NPIX);   // 8MB  fp8 [b][c][p]
  bf16_t* OT   = (bf16_t*)alloc((size_t)8 * NPIX * CH * 2);             // 16MB bf16 [b][p][c]
  bf16_t* wqb  = (bf16_t*)alloc(768 * 256 * 2);
  bf16_t* wpb  = (bf16_t*)alloc(256 * 256 * 2);
  float*  acc2 = (float*)alloc(64 * 2 * 4);
  float*  stats= (float*)alloc(64 * 2 * 4);
  bf16_t* xnT  = (bf16_t*)d_out;  // scratch: dead before final proj writes d_out

  hipMemsetAsync(acc2, 0, 64 * 2 * 4, stream);
  gn_partial_k<<<64 * 8, 256, 0, stream>>>(x, acc2);
  gn_finalize_k<<<1, 64, 0, stream>>>(acc2, stats);
  gn_apply_t_k<<<dim3(128, 8, 8), dim3(32, 8), 0, stream>>>(x, stats, gamma, beta, xnT);
  cast_w_k<<<768, 256, 0, stream>>>(w_qkv, w_proj, wqb, wpb);

  // QKV: [p][o] = xnT[p][c] . w_qkv[o][c]  -> fp8 q(prescaled)|k and v
  gemm_nt_k<0><<<dim3(32, 6, 8), 256, 0, stream>>>(xnT, wqb, CH, CH, CH,
                                                   qkT, vbuf, b_qkv, nullptr);
  // fused attention: 512 blocks x 256 thr (4 waves), 2 blocks/CU
  flash_k<<<512, 256, 0, stream>>>(qkT, vbuf, OT);

  // proj + bias + residual
  gemm_nt_k<3><<<dim3(2, 32, 8), 256, 0, stream>>>(wpb, OT, CH, CH, CH,
                                                   d_out, nullptr, b_proj, x);
}